// Round 5
// baseline (139.004 us; speedup 1.0000x reference)
//
#include <hip/hip_runtime.h>

typedef float f32x4 __attribute__((ext_vector_type(4)));
typedef short s16x8 __attribute__((ext_vector_type(8)));

constexpr int B  = 2;
constexpr int S  = 1025;
constexpr int D  = 768;
constexpr int DD = D * D;
constexpr int H  = 12;
constexpr int NM = 4;
constexpr int ROWS = B * S;              // 2050
constexpr int BSD  = B * S * D;          // 1,574,400
constexpr int SP   = 1088;               // padded S for Vt rows
constexpr int KPAD = 1088;               // padded key dim for mask table
constexpr int OUT_NEWH_OFF = BSD;
constexpr int OUT_IDX_OFF  = BSD + NM * BSD;
constexpr int OUT_NEWX_OFF = OUT_IDX_OFF + B * NM;

// fold 1/sqrt(64) into Q at projection time
#define QSCALE 0.125f

__device__ __forceinline__ unsigned short f2bf(float f) {
    unsigned u = __builtin_bit_cast(unsigned, f);
    u += 0x7FFF + ((u >> 16) & 1);          // RTNE (no NaN inputs here)
    return (unsigned short)(u >> 16);
}

// async global->LDS 16B copy (used by qkv GEMM staging)
__device__ __forceinline__ void gll16(const void* g, void* l) {
    __builtin_amdgcn_global_load_lds(
        (const __attribute__((address_space(1))) void*)g,
        (__attribute__((address_space(3))) void*)l, 16, 0, 0);
}

// ---------------------------------------------------------------------------
// Kernel 0: convert x, Wq/Wk/Wv to bf16; zero Vt padding; build bf16 mask
// bitmask table Mmb[b][v][k] (0xFFFF keep / 0x0000 drop, k in [0,KPAD)).
// xb/Wb live in the out_newx region of d_out (overwritten by tail_kernel).
// ---------------------------------------------------------------------------
__global__ __launch_bounds__(256) void conv_kernel(
    const float* __restrict__ x, const float* __restrict__ Wq,
    const float* __restrict__ Wk, const float* __restrict__ Wv,
    const int* __restrict__ masks,
    unsigned short* __restrict__ xb, unsigned short* __restrict__ Wb,
    unsigned short* __restrict__ Vt, unsigned short* __restrict__ Mmb)
{
    constexpr int NX8 = BSD / 8;        // 196800
    constexpr int NW8 = DD / 8;         // 73728
    constexpr int TOT = NX8 + 3 * NW8;  // 417984
    const int tid = blockIdx.x * 256 + threadIdx.x;
    for (int c = tid; c < TOT; c += gridDim.x * 256) {
        const float* src;
        unsigned short* dst;
        if (c < NX8) { src = x + (size_t)c * 8; dst = xb + (size_t)c * 8; }
        else {
            const int cc = c - NX8;
            const int mt = cc / NW8;
            const int rr = cc - mt * NW8;
            src = ((mt == 0) ? Wq : (mt == 1) ? Wk : Wv) + (size_t)rr * 8;
            dst = Wb + (size_t)mt * DD + (size_t)rr * 8;
        }
        const float4 a = *(const float4*)src;
        const float4 b2 = *(const float4*)(src + 4);
        s16x8 v;
        v[0] = (short)f2bf(a.x);  v[1] = (short)f2bf(a.y);
        v[2] = (short)f2bf(a.z);  v[3] = (short)f2bf(a.w);
        v[4] = (short)f2bf(b2.x); v[5] = (short)f2bf(b2.y);
        v[6] = (short)f2bf(b2.z); v[7] = (short)f2bf(b2.w);
        *(s16x8*)dst = v;
    }
    constexpr int NPADC = SP - S;              // 63
    constexpr int NPAD = B * H * 64 * NPADC;   // 96768
    if (tid < NPAD) {
        const int row = tid / NPADC;
        const int s = S + (tid % NPADC);
        Vt[(size_t)row * SP + s] = 0;
    }
    if (tid < B * NM * KPAD) {                 // 8704
        const int k  = tid % KPAD;
        const int bv = tid / KPAD;
        const int m = (k >= 1 && k < S) ? masks[(size_t)bv * (S - 1) + k - 1] : 0;
        Mmb[tid] = m ? 0xFFFFu : 0u;
    }
}

// ---------------------------------------------------------------------------
// Kernel 1: QKV projection, bf16 MFMA GEMM, double-buffered gll staging.
// Q is pre-scaled by QSCALE. V stored transposed: Vt[((b*H+h)*64+d)*SP + s].
// ---------------------------------------------------------------------------
__global__ __launch_bounds__(256, 2) void qkv_mfma_kernel(
    const unsigned short* __restrict__ xb, const unsigned short* __restrict__ Wb,
    const float* __restrict__ bq, const float* __restrict__ bk,
    const float* __restrict__ bv,
    unsigned short* __restrict__ Qb, unsigned short* __restrict__ Kb,
    unsigned short* __restrict__ Vt)
{
    __shared__ __align__(16) unsigned short Xs[2][64 * 64];
    __shared__ __align__(16) unsigned short Wl[2][64 * 64];

    const int t = threadIdx.x;
    const int row0 = blockIdx.x * 64;
    const int yy = blockIdx.y;
    const int mt = yy / 12;
    const int col0 = (yy % 12) * 64;
    const float* bias = (mt == 0) ? bq : (mt == 1) ? bk : bv;
    const unsigned short* Wsrc = Wb + (size_t)mt * DD;

    const int w = t >> 6, l = t & 63, lq = l & 15, grp = l >> 4;

    auto stage = [&](int buf, int k0) {
        #pragma unroll
        for (int i = 0; i < 2; ++i) {
            const int slot = i * 256 + t;
            const int r = slot >> 3, cl = slot & 7;
            const int cg = cl ^ (r & 7);
            int row = row0 + r; if (row > ROWS - 1) row = ROWS - 1;
            gll16(xb + (size_t)row * D + k0 + cg * 8, &Xs[buf][slot * 8]);
            gll16(Wsrc + (size_t)(col0 + r) * D + k0 + cg * 8, &Wl[buf][slot * 8]);
        }
    };

    f32x4 acc[4] = {};
    stage(0, 0);

    for (int ks = 0; ks < 12; ++ks) {
        const int cur = ks & 1;
        __syncthreads();
        if (ks + 1 < 12) stage(cur ^ 1, (ks + 1) * 64);

        s16x8 a[2];
        const int xr = w * 16 + lq;
        #pragma unroll
        for (int kh = 0; kh < 2; ++kh)
            a[kh] = *(const s16x8*)&Xs[cur][xr * 64 + (((kh * 4 + grp) ^ (xr & 7)) * 8)];
        #pragma unroll
        for (int nt = 0; nt < 4; ++nt) {
            const int wr = nt * 16 + lq;
            #pragma unroll
            for (int kh = 0; kh < 2; ++kh) {
                s16x8 bfr = *(const s16x8*)&Wl[cur][wr * 64 + (((kh * 4 + grp) ^ (wr & 7)) * 8)];
                acc[nt] = __builtin_amdgcn_mfma_f32_16x16x32_bf16(a[kh], bfr, acc[nt], 0, 0, 0);
            }
        }
    }

    #pragma unroll
    for (int nt = 0; nt < 4; ++nt) {
        const int col = col0 + nt * 16 + lq;
        const float bv_ = bias[col];
        #pragma unroll
        for (int r = 0; r < 4; ++r) {
            const int row = row0 + w * 16 + grp * 4 + r;   // C row = (l>>4)*4+reg
            if (row >= ROWS) continue;
            const float raw = acc[nt][r] + bv_;
            if (mt == 0)      Qb[(size_t)row * D + col] = f2bf(raw * QSCALE);
            else if (mt == 1) Kb[(size_t)row * D + col] = f2bf(raw);
            else {
                const int bb = (row >= S) ? 1 : 0;
                const int s  = row - bb * S;
                const int hh = col >> 6, dd = col & 63;
                Vt[((size_t)((bb * H + hh) * 64 + dd)) * SP + s] = f2bf(raw);
            }
        }
    }
}

// ---------------------------------------------------------------------------
// Kernel 2: barrier-free MFMA attention. 1 wave per block; block = 16 q-rows
// of one (b,h). K/V/mask fragments register-staged directly from L2
// (issue-after-last-use prefetch); only P goes through (wave-private,
// ping-pong) LDS. Swapped QK^T (mfma(K,Q) -> P^T regs -> packed b64 P
// writes); swapped PV (mfma(V,P) -> O^T, float4 stores); per-variant sums
// via a ones-fragment MFMA (no shuffle reduce, no float mask table).
// XCD-bijective block swizzle clusters each head-batch's K/V in one L2.
// ---------------------------------------------------------------------------
__global__ __launch_bounds__(64) void attn_mfma_kernel(
    const unsigned short* __restrict__ Qb, const unsigned short* __restrict__ Kb,
    const unsigned short* __restrict__ Vt, const unsigned short* __restrict__ Mmb,
    float* __restrict__ out_h, float* __restrict__ out_newh)
{
    __shared__ __align__(16) unsigned short Pl[2][16 * 64];

    // 1560 blocks = 8 XCDs * 195; cluster 3 head-batches per XCD
    const int orig = blockIdx.x;
    const int wgid = (orig & 7) * 195 + (orig >> 3);
    const int hb = wgid / 65;            // b*H + h  (0..23)
    const int qt = wgid - hb * 65;       // 0..64
    const int b  = hb / H, hh = hb - b * H;
    const int q0 = qt * 16;

    const int l = threadIdx.x;           // 0..63
    const int lq = l & 15, grp = l >> 4;

    const unsigned short* Kbase = Kb + (size_t)(b * S) * D + hh * 64 + grp * 8;
    const unsigned short* Vbase = Vt + (size_t)hb * 64 * SP + grp * 8;
    const unsigned short* Mbase = Mmb + (size_t)b * NM * KPAD + grp * 8;

    // Q fragments (B operand): q = q0 + lq
    s16x8 qf[2] = {};
    if (q0 + lq < S) {
        const unsigned short* p = Qb + (size_t)(b * S + q0 + lq) * D + hh * 64 + grp * 8;
        qf[0] = *(const s16x8*)p;
        qf[1] = *(const s16x8*)(p + 32);
    }

    s16x8 onesf;
    #pragma unroll
    for (int i = 0; i < 8; ++i) onesf[i] = (short)0x3F80;   // bf16 1.0

    s16x8 kf[4][2];   // [kt][kh]  A-operand: key rows kt*16+lq
    s16x8 vf[4][2];   // [dt][kh]  A-operand: dim rows dt*16+lq

    auto load_k = [&](int k0) {
        #pragma unroll
        for (int kt = 0; kt < 4; ++kt) {
            int row = k0 + kt * 16 + lq; if (row > S - 1) row = S - 1;
            const unsigned short* p = Kbase + (size_t)row * D;
            kf[kt][0] = *(const s16x8*)p;
            kf[kt][1] = *(const s16x8*)(p + 32);
        }
    };
    auto load_v = [&](int k0) {
        #pragma unroll
        for (int dt = 0; dt < 4; ++dt) {
            const unsigned short* p = Vbase + (size_t)(dt * 16 + lq) * SP + k0;
            vf[dt][0] = *(const s16x8*)p;
            vf[dt][1] = *(const s16x8*)(p + 32);
        }
    };

    f32x4 acc[5][5] = {};   // [variant][dt 0..3 = O^T tiles, 4 = sums]

    load_k(0);
    load_v(0);

    constexpr int NT = 17;
    for (int it = 0; it < NT; ++it) {
        const int k0 = it * 64;
        unsigned short* P = &Pl[it & 1][0];

        // ---- QK^T (swapped): qk[kt] = P^T, lane holds col q=lq, rows=keys
        f32x4 qk[4] = {};
        #pragma unroll
        for (int kt = 0; kt < 4; ++kt)
            #pragma unroll
            for (int kh = 0; kh < 2; ++kh)
                qk[kt] = __builtin_amdgcn_mfma_f32_16x16x32_bf16(kf[kt][kh], qf[kh], qk[kt], 0, 0, 0);

        // prefetch next K tile (kf free after QK^T; covered by exp+PV)
        if (it + 1 < NT) load_k(k0 + 64);

        // ---- exp + pack 4 consecutive keys -> one b64 P write per kt ----
        #pragma unroll
        for (int kt = 0; kt < 4; ++kt) {
            float e[4];
            #pragma unroll
            for (int r = 0; r < 4; ++r) {
                const int key = k0 + kt * 16 + grp * 4 + r;
                e[r] = (key < S) ? __expf(qk[kt][r]) : 0.f;
            }
            const unsigned p01 = (unsigned)f2bf(e[0]) | ((unsigned)f2bf(e[1]) << 16);
            const unsigned p23 = (unsigned)f2bf(e[2]) | ((unsigned)f2bf(e[3]) << 16);
            const int chunk = kt * 2 + (grp >> 1);
            *(uint2*)&P[lq * 64 + ((chunk ^ (lq & 7)) * 8) + (grp & 1) * 4] =
                make_uint2(p01, p23);
        }

        // ---- PV (swapped, O^T) + ones-MFMA sums ----
        #pragma unroll
        for (int kh = 0; kh < 2; ++kh) {
            // mask bitmasks for this k-half (L1-resident broadcast loads)
            s16x8 mm[4];
            #pragma unroll
            for (int v = 0; v < 4; ++v)
                mm[v] = *(const s16x8*)(Mbase + (size_t)v * KPAD + k0 + kh * 32);

            s16x8 pa[5];
            pa[0] = *(const s16x8*)&P[lq * 64 + (((kh * 4 + grp) ^ (lq & 7)) * 8)];
            #pragma unroll
            for (int v = 1; v < 5; ++v) pa[v] = pa[0] & mm[v - 1];

            #pragma unroll
            for (int dt = 0; dt < 4; ++dt)
                #pragma unroll
                for (int v = 0; v < 5; ++v)
                    acc[v][dt] = __builtin_amdgcn_mfma_f32_16x16x32_bf16(vf[dt][kh], pa[v], acc[v][dt], 0, 0, 0);
            #pragma unroll
            for (int v = 0; v < 5; ++v)
                acc[v][4] = __builtin_amdgcn_mfma_f32_16x16x32_bf16(onesf, pa[v], acc[v][4], 0, 0, 0);
        }

        // prefetch next V tile (vf free after PV; covered by next QK+exp)
        if (it + 1 < NT) load_v(k0 + 64);
    }

    // ---- normalize + store: O^T layout -> q=lq, d = dt*16 + grp*4 + r ----
    const int q = q0 + lq;
    if (q < S) {
        #pragma unroll
        for (int v = 0; v < 5; ++v) {
            const float inv = 1.0f / acc[v][4][0];
            float* base = ((v == 0)
                ? out_h    + (size_t)(b * S + q) * D
                : out_newh + (size_t)((b * NM + v - 1) * S + q) * D) + hh * 64 + grp * 4;
            #pragma unroll
            for (int dt = 0; dt < 4; ++dt) {
                float4 o;
                o.x = acc[v][dt][0] * inv; o.y = acc[v][dt][1] * inv;
                o.z = acc[v][dt][2] * inv; o.w = acc[v][dt][3] * inv;
                *(float4*)(base + dt * 16) = o;
            }
        }
    }
}

// ---------------------------------------------------------------------------
// Kernel 3: new_x broadcast copy + img_idx (runs LAST: overwrites the
// out_newx region that conv/qkv used as bf16 scratch).
// ---------------------------------------------------------------------------
__global__ __launch_bounds__(256) void tail_kernel(
    const float* __restrict__ x, float* __restrict__ out_newx,
    float* __restrict__ out_idx)
{
    const int SLAB4  = S * D / 4;
    const int TOTAL4 = B * NM * SLAB4;
    const float4* x4 = (const float4*)x;
    float4* o4 = (float4*)out_newx;
    for (int f = blockIdx.x * blockDim.x + threadIdx.x; f < TOTAL4;
         f += gridDim.x * blockDim.x) {
        const int bm  = f / SLAB4;
        const int rem = f - bm * SLAB4;
        o4[f] = x4[(bm >> 2) * SLAB4 + rem];
    }
    const int idx = blockIdx.x * blockDim.x + threadIdx.x;
    if (idx < B * NM) out_idx[idx] = (float)(idx >> 2);
}

// ---------------------------------------------------------------------------
extern "C" void kernel_launch(void* const* d_in, const int* in_sizes, int n_in,
                              void* d_out, int out_size, void* d_ws, size_t ws_size,
                              hipStream_t stream)
{
    const float* x     = (const float*)d_in[0];
    const int*   masks = (const int*)  d_in[1];
    const float* Wq    = (const float*)d_in[2];
    const float* bq    = (const float*)d_in[3];
    const float* Wk    = (const float*)d_in[4];
    const float* bk    = (const float*)d_in[5];
    const float* Wv    = (const float*)d_in[6];
    const float* bv    = (const float*)d_in[7];

    float* out = (float*)d_out;
    float* out_h    = out;
    float* out_newh = out + OUT_NEWH_OFF;
    float* out_idx  = out + OUT_IDX_OFF;
    float* out_newx = out + OUT_NEWX_OFF;

    unsigned short* Qb  = (unsigned short*)d_ws;
    unsigned short* Kb  = Qb + BSD;
    unsigned short* Vt  = Kb + BSD;                  // B*H*64*SP
    unsigned short* Mmb = Vt + (size_t)B * H * 64 * SP;  // B*NM*KPAD

    // bf16 scratch aliased into the out_newx region (rewritten by tail_kernel)
    unsigned short* xb = (unsigned short*)out_newx;
    unsigned short* Wb = xb + BSD;

    conv_kernel<<<1634, 256, 0, stream>>>(x, Wq, Wk, Wv, masks, xb, Wb, Vt, Mmb);
    {
        dim3 grid(33, 36);
        qkv_mfma_kernel<<<grid, 256, 0, stream>>>(xb, Wb, bq, bk, bv, Qb, Kb, Vt);
    }
    attn_mfma_kernel<<<1560, 64, 0, stream>>>(Qb, Kb, Vt, Mmb, out_h, out_newh);
    tail_kernel<<<2048, 256, 0, stream>>>(x, out_newx, out_idx);
}

// Round 6
// 115.113 us; speedup vs baseline: 1.2076x; 1.2076x over previous
//
#include <hip/hip_runtime.h>

typedef float f32x4 __attribute__((ext_vector_type(4)));
typedef short s16x8 __attribute__((ext_vector_type(8)));

constexpr int B  = 2;
constexpr int S  = 1025;
constexpr int D  = 768;
constexpr int DD = D * D;
constexpr int H  = 12;
constexpr int NM = 4;
constexpr int ROWS = B * S;              // 2050
constexpr int BSD  = B * S * D;          // 1,574,400
constexpr int KPAD = 1088;               // padded key dim for mask table
constexpr int NHB  = B * H;              // 24
constexpr int NQT  = 65;                 // q-tiles of 16
constexpr int NKT  = 17;                 // key-tiles of 64
constexpr int OUT_NEWH_OFF = BSD;
constexpr int OUT_IDX_OFF  = BSD + NM * BSD;
constexpr int OUT_NEWX_OFF = OUT_IDX_OFF + B * NM;

#define QSCALE 0.125f

// fragment array sizes (u16 elements)
constexpr size_t QF_SZ = (size_t)NHB * NQT * 2 * 512;        // 1,597,440
constexpr size_t KF_SZ = (size_t)NHB * NKT * 4 * 2 * 512;    // 1,671,168
constexpr size_t VF_SZ = KF_SZ;

__device__ __forceinline__ unsigned short f2bf(float f) {
    unsigned u = __builtin_bit_cast(unsigned, f);
    u += 0x7FFF + ((u >> 16) & 1);          // RTNE
    return (unsigned short)(u >> 16);
}

__device__ __forceinline__ void gll16(const void* g, void* l) {
    __builtin_amdgcn_global_load_lds(
        (const __attribute__((address_space(1))) void*)g,
        (__attribute__((address_space(3))) void*)l, 16, 0, 0);
}

// ---------------------------------------------------------------------------
// Kernel 0: convert x, Wq/Wk/Wv to bf16; build bf16 mask bitmask table.
// xb/Wb live in the out_newx region of d_out (overwritten by tail_kernel).
// ---------------------------------------------------------------------------
__global__ __launch_bounds__(256) void conv_kernel(
    const float* __restrict__ x, const float* __restrict__ Wq,
    const float* __restrict__ Wk, const float* __restrict__ Wv,
    const int* __restrict__ masks,
    unsigned short* __restrict__ xb, unsigned short* __restrict__ Wb,
    unsigned short* __restrict__ Mmb)
{
    constexpr int NX8 = BSD / 8;        // 196800
    constexpr int NW8 = DD / 8;         // 73728
    constexpr int TOT = NX8 + 3 * NW8;  // 417984
    const int tid = blockIdx.x * 256 + threadIdx.x;
    for (int c = tid; c < TOT; c += gridDim.x * 256) {
        const float* src;
        unsigned short* dst;
        if (c < NX8) { src = x + (size_t)c * 8; dst = xb + (size_t)c * 8; }
        else {
            const int cc = c - NX8;
            const int mt = cc / NW8;
            const int rr = cc - mt * NW8;
            src = ((mt == 0) ? Wq : (mt == 1) ? Wk : Wv) + (size_t)rr * 8;
            dst = Wb + (size_t)mt * DD + (size_t)rr * 8;
        }
        const float4 a = *(const float4*)src;
        const float4 b2 = *(const float4*)(src + 4);
        s16x8 v;
        v[0] = (short)f2bf(a.x);  v[1] = (short)f2bf(a.y);
        v[2] = (short)f2bf(a.z);  v[3] = (short)f2bf(a.w);
        v[4] = (short)f2bf(b2.x); v[5] = (short)f2bf(b2.y);
        v[6] = (short)f2bf(b2.z); v[7] = (short)f2bf(b2.w);
        *(s16x8*)dst = v;
    }
    if (tid < B * NM * KPAD) {                 // 8704
        const int k  = tid % KPAD;
        const int bv = tid / KPAD;
        const int m = (k >= 1 && k < S) ? masks[(size_t)bv * (S - 1) + k - 1] : 0;
        Mmb[tid] = m ? 0xFFFFu : 0u;
    }
}

// ---------------------------------------------------------------------------
// Kernel 1: QKV projection, bf16 MFMA GEMM, double-buffered gll staging.
// Epilogue writes Q/K/V in MFMA FRAGMENT ORDER so attention loads are
// fully coalesced 1KB bursts:
//   Qf[hb][qt][kh][lane][8]  elem = Q[qt*16+(l&15)][(l>>4)*8+kh*32+e]*QSCALE
//   Kf[hb][tile][kt][kh][lane][8] = K[tile*64+kt*16+(l&15)][(l>>4)*8+kh*32+e]
//   Vf[hb][tile][dt][kh][lane][8] = V[tile*64+(l>>4)*8+kh*32+e][dt*16+(l&15)]
// ---------------------------------------------------------------------------
__global__ __launch_bounds__(256, 2) void qkv_mfma_kernel(
    const unsigned short* __restrict__ xb, const unsigned short* __restrict__ Wb,
    const float* __restrict__ bq, const float* __restrict__ bk,
    const float* __restrict__ bv,
    unsigned short* __restrict__ Qf, unsigned short* __restrict__ Kf,
    unsigned short* __restrict__ Vf)
{
    __shared__ __align__(16) unsigned short Xs[2][64 * 64];
    __shared__ __align__(16) unsigned short Wl[2][64 * 64];

    const int t = threadIdx.x;
    const int row0 = blockIdx.x * 64;
    const int yy = blockIdx.y;
    const int mt = yy / 12;
    const int col0 = (yy % 12) * 64;
    const float* bias = (mt == 0) ? bq : (mt == 1) ? bk : bv;
    const unsigned short* Wsrc = Wb + (size_t)mt * DD;

    const int w = t >> 6, l = t & 63, lq = l & 15, grp = l >> 4;

    auto stage = [&](int buf, int k0) {
        #pragma unroll
        for (int i = 0; i < 2; ++i) {
            const int slot = i * 256 + t;
            const int r = slot >> 3, cl = slot & 7;
            const int cg = cl ^ (r & 7);
            int row = row0 + r; if (row > ROWS - 1) row = ROWS - 1;
            gll16(xb + (size_t)row * D + k0 + cg * 8, &Xs[buf][slot * 8]);
            gll16(Wsrc + (size_t)(col0 + r) * D + k0 + cg * 8, &Wl[buf][slot * 8]);
        }
    };

    f32x4 acc[4] = {};
    stage(0, 0);

    for (int ks = 0; ks < 12; ++ks) {
        const int cur = ks & 1;
        __syncthreads();
        if (ks + 1 < 12) stage(cur ^ 1, (ks + 1) * 64);

        s16x8 a[2];
        const int xr = w * 16 + lq;
        #pragma unroll
        for (int kh = 0; kh < 2; ++kh)
            a[kh] = *(const s16x8*)&Xs[cur][xr * 64 + (((kh * 4 + grp) ^ (xr & 7)) * 8)];
        #pragma unroll
        for (int nt = 0; nt < 4; ++nt) {
            const int wr = nt * 16 + lq;
            #pragma unroll
            for (int kh = 0; kh < 2; ++kh) {
                s16x8 bfr = *(const s16x8*)&Wl[cur][wr * 64 + (((kh * 4 + grp) ^ (wr & 7)) * 8)];
                acc[nt] = __builtin_amdgcn_mfma_f32_16x16x32_bf16(a[kh], bfr, acc[nt], 0, 0, 0);
            }
        }
    }

    #pragma unroll
    for (int nt = 0; nt < 4; ++nt) {
        const int col = col0 + nt * 16 + lq;
        const float bv_ = bias[col];
        #pragma unroll
        for (int r = 0; r < 4; ++r) {
            const int row = row0 + w * 16 + grp * 4 + r;   // C row = (l>>4)*4+reg
            if (row >= ROWS) continue;
            const float raw = acc[nt][r] + bv_;
            const int bb = (row >= S) ? 1 : 0;
            const int s  = row - bb * S;
            const int hb2 = bb * H + (col >> 6);
            const int d   = col & 63;
            if (mt == 0) {
                const size_t idx = (((size_t)(hb2 * NQT + (s >> 4)) * 2 + (d >> 5)) << 9)
                                 + (((((d >> 3) & 3) << 4) + (s & 15)) << 3) + (d & 7);
                Qf[idx] = f2bf(raw * QSCALE);
            } else if (mt == 1) {
                const size_t idx = ((((size_t)(hb2 * NKT + (s >> 6)) * 4 + ((s >> 4) & 3)) * 2 + (d >> 5)) << 9)
                                 + (((((d >> 3) & 3) << 4) + (s & 15)) << 3) + (d & 7);
                Kf[idx] = f2bf(raw);
            } else {
                const int kk = s & 63;
                const size_t idx = ((((size_t)(hb2 * NKT + (s >> 6)) * 4 + (d >> 4)) * 2 + (kk >> 5)) << 9)
                                 + (((((kk >> 3) & 3) << 4) + (d & 15)) << 3) + (kk & 7);
                Vf[idx] = f2bf(raw);
            }
        }
    }
}

// ---------------------------------------------------------------------------
// Kernel 2: MFMA attention. 128-thr blocks = 2 waves over the SAME 16 q-rows,
// split over key tiles (wave w does tiles w, w+2, ...). All operand loads are
// coalesced fragment loads from Qf/Kf/Vf (issue-after-last-use prefetch).
// Swapped QK^T -> packed P via wave-private LDS -> masked-bitmask PV +
// ones-MFMA sums. Final cross-wave combine via small LDS chunks (additive:
// no max-subtraction, so partial acc/sums just add). XCD-bijective swizzle.
// ---------------------------------------------------------------------------
__global__ __launch_bounds__(128) void attn_mfma_kernel(
    const unsigned short* __restrict__ Qf, const unsigned short* __restrict__ Kf,
    const unsigned short* __restrict__ Vf, const unsigned short* __restrict__ Mmb,
    float* __restrict__ out_h, float* __restrict__ out_newh)
{
    __shared__ __align__(16) unsigned short Pl[2][16 * 64];  // per-wave P tile
    __shared__ __align__(16) float Cl[64][24];               // combine chunk

    // 1560 blocks = 8 XCDs * 195 (bijective)
    const int orig = blockIdx.x;
    const int wgid = (orig & 7) * 195 + (orig >> 3);
    const int hb = wgid / NQT;           // 0..23
    const int qt = wgid - hb * NQT;      // 0..64
    const int b  = hb / H, hh = hb - b * H;
    const int q0 = qt * 16;

    const int t = threadIdx.x;
    const int w = t >> 6, l = t & 63;
    const int lq = l & 15, grp = l >> 4;

    // Q fragments (coalesced 1KB per kh)
    s16x8 qf[2];
    {
        const unsigned short* p = Qf + (((size_t)(hb * NQT + qt) * 2) << 9) + (l << 3);
        qf[0] = *(const s16x8*)p;
        qf[1] = *(const s16x8*)(p + 512);
    }

    const unsigned short* Mbase = Mmb + (size_t)b * NM * KPAD + grp * 8;

    s16x8 onesf;
    #pragma unroll
    for (int i = 0; i < 8; ++i) onesf[i] = (short)0x3F80;   // bf16 1.0

    s16x8 kf[4][2], vf[4][2];

    auto load_k = [&](int tile) {
        #pragma unroll
        for (int kt = 0; kt < 4; ++kt)
            #pragma unroll
            for (int kh = 0; kh < 2; ++kh)
                kf[kt][kh] = *(const s16x8*)&Kf[((((size_t)(hb * NKT + tile) * 4 + kt) * 2 + kh) << 9) + (l << 3)];
    };
    auto load_v = [&](int tile) {
        #pragma unroll
        for (int dt = 0; dt < 4; ++dt)
            #pragma unroll
            for (int kh = 0; kh < 2; ++kh)
                vf[dt][kh] = *(const s16x8*)&Vf[((((size_t)(hb * NKT + tile) * 4 + dt) * 2 + kh) << 9) + (l << 3)];
    };

    f32x4 acc[5][5] = {};   // [variant][0..3 = O^T d-tiles, 4 = sums]

    load_k(w);
    load_v(w);

    for (int it = w; it < NKT; it += 2) {
        const int k0 = it * 64;
        unsigned short* P = &Pl[w][0];

        // ---- QK^T (swapped): C col = q (lane&15), rows = keys ----
        f32x4 qk[4] = {};
        #pragma unroll
        for (int kt = 0; kt < 4; ++kt)
            #pragma unroll
            for (int kh = 0; kh < 2; ++kh)
                qk[kt] = __builtin_amdgcn_mfma_f32_16x16x32_bf16(kf[kt][kh], qf[kh], qk[kt], 0, 0, 0);

        if (it + 2 < NKT) load_k(it + 2);   // prefetch, covered by exp+PV

        // ---- exp + pack 4 consecutive keys -> one b64 P write per kt ----
        #pragma unroll
        for (int kt = 0; kt < 4; ++kt) {
            float e[4];
            #pragma unroll
            for (int r = 0; r < 4; ++r) {
                const int key = k0 + kt * 16 + grp * 4 + r;
                e[r] = (key < S) ? __expf(qk[kt][r]) : 0.f;
            }
            const unsigned p01 = (unsigned)f2bf(e[0]) | ((unsigned)f2bf(e[1]) << 16);
            const unsigned p23 = (unsigned)f2bf(e[2]) | ((unsigned)f2bf(e[3]) << 16);
            const int chunk = kt * 2 + (grp >> 1);
            *(uint2*)&P[lq * 64 + ((chunk ^ (lq & 7)) * 8) + (grp & 1) * 4] =
                make_uint2(p01, p23);
        }

        // ---- PV (swapped, O^T) + ones-MFMA sums ----
        #pragma unroll
        for (int kh = 0; kh < 2; ++kh) {
            s16x8 mm[4];
            #pragma unroll
            for (int v = 0; v < 4; ++v)
                mm[v] = *(const s16x8*)(Mbase + (size_t)v * KPAD + k0 + kh * 32);

            s16x8 pa[5];
            pa[0] = *(const s16x8*)&P[lq * 64 + (((kh * 4 + grp) ^ (lq & 7)) * 8)];
            #pragma unroll
            for (int v = 1; v < 5; ++v) pa[v] = pa[0] & mm[v - 1];

            #pragma unroll
            for (int dt = 0; dt < 4; ++dt)
                #pragma unroll
                for (int v = 0; v < 5; ++v)
                    acc[v][dt] = __builtin_amdgcn_mfma_f32_16x16x32_bf16(vf[dt][kh], pa[v], acc[v][dt], 0, 0, 0);
            #pragma unroll
            for (int v = 0; v < 5; ++v)
                acc[v][4] = __builtin_amdgcn_mfma_f32_16x16x32_bf16(onesf, pa[v], acc[v][4], 0, 0, 0);
        }

        if (it + 2 < NKT) load_v(it + 2);   // prefetch, covered by next QK+exp
    }

    // ---- cross-wave combine (additive) + normalize + store, per variant ----
    const int q = q0 + lq;
    #pragma unroll
    for (int v = 0; v < 5; ++v) {
        if (w == 1) {
            #pragma unroll
            for (int j = 0; j < 5; ++j) *(f32x4*)&Cl[l][j * 4] = acc[v][j];
        }
        __syncthreads();
        if (w == 0) {
            const float sum = acc[v][4][0] + Cl[l][16];
            const float inv = 1.0f / sum;
            if (q < S) {
                float* base = ((v == 0)
                    ? out_h    + (size_t)(b * S + q) * D
                    : out_newh + (size_t)((b * NM + v - 1) * S + q) * D) + hh * 64 + grp * 4;
                #pragma unroll
                for (int dt = 0; dt < 4; ++dt) {
                    const f32x4 o = acc[v][dt] + *(const f32x4*)&Cl[l][dt * 4];
                    float4 s4;
                    s4.x = o[0] * inv; s4.y = o[1] * inv;
                    s4.z = o[2] * inv; s4.w = o[3] * inv;
                    *(float4*)(base + dt * 16) = s4;
                }
            }
        }
        __syncthreads();
    }
}

// ---------------------------------------------------------------------------
// Kernel 3: new_x broadcast copy + img_idx (runs LAST: overwrites the
// out_newx region that conv/qkv used as bf16 scratch).
// ---------------------------------------------------------------------------
__global__ __launch_bounds__(256) void tail_kernel(
    const float* __restrict__ x, float* __restrict__ out_newx,
    float* __restrict__ out_idx)
{
    const int SLAB4  = S * D / 4;
    const int TOTAL4 = B * NM * SLAB4;
    const float4* x4 = (const float4*)x;
    float4* o4 = (float4*)out_newx;
    for (int f = blockIdx.x * blockDim.x + threadIdx.x; f < TOTAL4;
         f += gridDim.x * blockDim.x) {
        const int bm  = f / SLAB4;
        const int rem = f - bm * SLAB4;
        o4[f] = x4[(bm >> 2) * SLAB4 + rem];
    }
    const int idx = blockIdx.x * blockDim.x + threadIdx.x;
    if (idx < B * NM) out_idx[idx] = (float)(idx >> 2);
}

// ---------------------------------------------------------------------------
extern "C" void kernel_launch(void* const* d_in, const int* in_sizes, int n_in,
                              void* d_out, int out_size, void* d_ws, size_t ws_size,
                              hipStream_t stream)
{
    const float* x     = (const float*)d_in[0];
    const int*   masks = (const int*)  d_in[1];
    const float* Wq    = (const float*)d_in[2];
    const float* bq    = (const float*)d_in[3];
    const float* Wk    = (const float*)d_in[4];
    const float* bk    = (const float*)d_in[5];
    const float* Wv    = (const float*)d_in[6];
    const float* bv    = (const float*)d_in[7];

    float* out = (float*)d_out;
    float* out_h    = out;
    float* out_newh = out + OUT_NEWH_OFF;
    float* out_idx  = out + OUT_IDX_OFF;
    float* out_newx = out + OUT_NEWX_OFF;

    unsigned short* Qf  = (unsigned short*)d_ws;
    unsigned short* Kf  = Qf + QF_SZ;
    unsigned short* Vf  = Kf + KF_SZ;
    unsigned short* Mmb = Vf + VF_SZ;      // B*NM*KPAD

    // bf16 scratch aliased into the out_newx region (rewritten by tail_kernel)
    unsigned short* xb = (unsigned short*)out_newx;
    unsigned short* Wb = xb + BSD;

    conv_kernel<<<1634, 256, 0, stream>>>(x, Wq, Wk, Wv, masks, xb, Wb, Mmb);
    {
        dim3 grid(33, 36);
        qkv_mfma_kernel<<<grid, 256, 0, stream>>>(xb, Wb, bq, bk, bv, Qf, Kf, Vf);
    }
    attn_mfma_kernel<<<1560, 128, 0, stream>>>(Qf, Kf, Vf, Mmb, out_h, out_newh);
    tail_kernel<<<2048, 256, 0, stream>>>(x, out_newx, out_idx);
}